// Round 11
// baseline (387.304 us; speedup 1.0000x reference)
//
#include <hip/hip_runtime.h>
#include <math.h>

#define B_   16
#define S_   1056
#define SP_  1088             // k padded to 34*32
#define DM_  256
#define H_   8
#define DK_  32
#define TXT_ 32
#define VID_ 1024
#define SS_  (S_*S_)          // 1115136
#define NQT_ 66               // q-tiles of 16 rows

#define LOG2_10000f 13.28771237954945f
#define LOG2_GAMMAf (-0.15200309344504995f)   // log2(0.9)
#define RSQRT_DKf   0.17677669529663687f      // 1/sqrt(32)
#define TWO_PIf     6.283185307179586f

typedef __attribute__((ext_vector_type(8))) short bf16x8;
typedef __attribute__((ext_vector_type(4))) short bf16x4;
typedef __attribute__((ext_vector_type(4))) float f32x4;

__device__ __forceinline__ short f2bf(float f){
    unsigned u = __float_as_uint(f);
    unsigned r = u + 0x7FFFu + ((u >> 16) & 1u);   // RNE
    return (short)(r >> 16);
}
__device__ __forceinline__ float bf2f(unsigned short s){
    return __uint_as_float(((unsigned)s) << 16);
}

// K=16 bf16 MFMA: A-frag lane(lr,lg) holds A[row=lr][k=4lg+j] — exactly the
// D-layout of the QK^T tile (P[q=lr][k=4lg+r]), so P feeds PV in-lane.
__device__ __forceinline__ f32x4 mfma16(bf16x4 a, bf16x4 b, f32x4 c){
#if __has_builtin(__builtin_amdgcn_mfma_f32_16x16x16bf16_1k)
    return __builtin_amdgcn_mfma_f32_16x16x16bf16_1k(a, b, c, 0, 0, 0);
#else
    f32x4 d = c;
    asm volatile("v_mfma_f32_16x16x16_bf16 %0, %1, %2, %0" : "+v"(d) : "v"(a), "v"(b));
    return d;
#endif
}

// ---------------- mask (bf16) + loss partials ----------------
__global__ __launch_bounds__(256) void k_mask(const float* __restrict__ lvr,
                       const int* __restrict__ row_idx, const int* __restrict__ col_idx,
                       short* __restrict__ maskb, float* __restrict__ partials)
{
    int idx = blockIdx.x*256 + threadIdx.x;
    unsigned ui = (unsigned)idx;
    int i = ui / S_;
    int j = (int)(ui - (unsigned)i*S_);
    float vr, lm;
    if (i == j) { vr = 0.f; lm = 1.f; }
    else {
        float t = lvr[(size_t)row_idx[idx]*VID_ + col_idx[idx]];
        float sg = 1.f/(1.f + expf(-t));
        vr = sg; lm = sg;
    }
    float dmat = (i >= j) ? exp2f((float)(i-j)*LOG2_GAMMAf) : 0.f;
    maskb[idx] = f2bf(dmat * lm);
    float s = vr;
    #pragma unroll
    for (int m=1; m<64; m<<=1) s += __shfl_xor(s, m, 64);
    __shared__ float ws4[4];
    if ((threadIdx.x & 63) == 0) ws4[threadIdx.x>>6] = s;
    __syncthreads();
    if (threadIdx.x == 0) partials[blockIdx.x] = ws4[0]+ws4[1]+ws4[2]+ws4[3];
}

__global__ __launch_bounds__(256) void k_loss(const float* __restrict__ partials,
                                              float* __restrict__ out_loss)
{
    float s = 0.f;
    for (int i = threadIdx.x; i < SS_/256; i += 256) s += partials[i];
    #pragma unroll
    for (int m=1; m<64; m<<=1) s += __shfl_xor(s, m, 64);
    __shared__ float ws4[4];
    if ((threadIdx.x & 63) == 0) ws4[threadIdx.x>>6] = s;
    __syncthreads();
    if (threadIdx.x == 0) out_loss[0] = (ws4[0]+ws4[1]+ws4[2]+ws4[3]) * (1.f/(float)SS_);
}

// ---------------- weight prep ----------------
__global__ __launch_bounds__(256) void k_wprep(
    const float* __restrict__ Wtq, const float* __restrict__ Wtk, const float* __restrict__ Wtv,
    const float* __restrict__ Wvq, const float* __restrict__ Wvk, const float* __restrict__ Wvv,
    const float* __restrict__ Wout, short* __restrict__ WTall, short* __restrict__ WoB)
{
    int seg = blockIdx.x >> 8;
    int r   = blockIdx.x & 255;
    int tid = threadIdx.x;
    if (seg == 6) {
        WoB[r*256 + tid] = f2bf(Wout[r*256 + tid]);
    } else {
        const float* Wsrc = seg==0?Wtq: seg==1?Wtk: seg==2?Wtv: seg==3?Wvq: seg==4?Wvk: Wvv;
        WTall[(size_t)seg*65536 + r*256 + tid] = f2bf(Wsrc[tid*256 + r]);
    }
}

// ---------------- QKV projection via MFMA (unchanged, passing) ----------------
__global__ __launch_bounds__(256, 2) void k_qkv(const float* __restrict__ src,
    const short* __restrict__ WTq, const short* __restrict__ WTk, const short* __restrict__ WTv,
    short* __restrict__ Qb, short* __restrict__ Kb, short* __restrict__ VT, int is_txt)
{
    __shared__ __align__(16) short xb[3][16][256];   // 24 KB
    __shared__ float invf[128];
    __shared__ float lbs[128];
    int tid = threadIdx.x;
    int r0 = blockIdx.x * 16;
    int b, srow0;
    if (is_txt) { b = r0 >> 5;  srow0 = r0 & 31; }
    else        { b = r0 >> 10; srow0 = TXT_ + (r0 & 1023); }

    if (tid < 128) {
        float fk = (float)tid;
        invf[tid] = exp2f(-fk*(1.f/128.f)*LOG2_10000f);
        lbs[tid]  = log2f((2.f*fk + 102.4f) * (1.f/358.4f));
    }
    __syncthreads();

    #pragma unroll
    for (int it = 0; it < 8; ++it) {
        int task = it*256 + tid;
        int k  = task >> 4;
        int rr = task & 15;
        int srow = srow0 + rr;
        float2 x01 = ((const float2*)(src + ((size_t)b*S_ + srow)*DM_))[k];
        float a0, a1, c0, c1;
        if (is_txt) {
            float xe  = (float)(srow + 1) * (TWO_PIf/(32.f + 1e-6f));
            float arg = xe * invf[k];
            float sn = __sinf(arg), cs = __cosf(arg);
            a0 = x01.x + sn; a1 = x01.y + cs;
            c0 = a0; c1 = a1;
        } else {
            int l = srow - TXT_;
            float arg = (float)l * invf[k];
            float sn = __sinf(arg), cs = __cosf(arg);
            float scale = exp2f((float)l*(1.f/512.f)*lbs[k]);
            float rsc = 1.f/scale;
            float y0 = x01.x*cs - x01.y*sn;
            float y1 = x01.y*cs + x01.x*sn;
            a0 = y0*scale; a1 = y1*scale;
            c0 = y0*rsc;   c1 = y1*rsc;
        }
        int col = (2*k) ^ ((rr&7)<<3);
        *(short2*)&xb[0][rr][col] = make_short2(f2bf(a0), f2bf(a1));
        *(short2*)&xb[1][rr][col] = make_short2(f2bf(c0), f2bf(c1));
        *(short2*)&xb[2][rr][col] = make_short2(f2bf(x01.x), f2bf(x01.y));
    }
    __syncthreads();

    int lane = tid & 63;
    int w    = tid >> 6;
    int lr   = lane & 15;
    int lg   = lane >> 4;
    int swzl = (lr & 7) << 3;

    const short* WTs[3] = {WTq, WTk, WTv};
    #pragma unroll
    for (int m = 0; m < 3; ++m) {
        bf16x8 xf[8];
        #pragma unroll
        for (int kk = 0; kk < 8; ++kk)
            xf[kk] = *(const bf16x8*)&xb[m][lr][(kk*32 + lg*8) ^ swzl];
        #pragma unroll
        for (int ct = 0; ct < 4; ++ct) {
            int tb = (w + ct*4) * 16;
            const short* Wp = WTs[m] + (size_t)(tb+lr)*DM_ + lg*8;
            f32x4 acc = {0.f,0.f,0.f,0.f};
            if (m < 2) {
                #pragma unroll
                for (int kk = 0; kk < 8; ++kk) {
                    bf16x8 wf = *(const bf16x8*)(Wp + kk*32);
                    acc = __builtin_amdgcn_mfma_f32_16x16x32_bf16(wf, xf[kk], acc, 0, 0, 0);
                }
                int h  = tb >> 5;
                int d0 = (tb & 31) + lg*4;
                size_t off = ((size_t)(b*H_+h)*S_ + srow0+lr)*DK_ + d0;
                short4 s4;
                if (m == 0) {
                    s4.x=f2bf(acc[0]*RSQRT_DKf); s4.y=f2bf(acc[1]*RSQRT_DKf);
                    s4.z=f2bf(acc[2]*RSQRT_DKf); s4.w=f2bf(acc[3]*RSQRT_DKf);
                    *(short4*)&Qb[off] = s4;
                } else {
                    s4.x=f2bf(acc[0]); s4.y=f2bf(acc[1]);
                    s4.z=f2bf(acc[2]); s4.w=f2bf(acc[3]);
                    *(short4*)&Kb[off] = s4;
                }
            } else {
                #pragma unroll
                for (int kk = 0; kk < 8; ++kk) {
                    bf16x8 wf = *(const bf16x8*)(Wp + kk*32);
                    acc = __builtin_amdgcn_mfma_f32_16x16x32_bf16(xf[kk], wf, acc, 0, 0, 0);
                }
                int o = tb + lr;
                int h = o >> 5, d = o & 31;
                short4 s4;
                s4.x=f2bf(acc[0]); s4.y=f2bf(acc[1]);
                s4.z=f2bf(acc[2]); s4.w=f2bf(acc[3]);
                *(short4*)&VT[((size_t)(b*H_+h)*DK_ + d)*SP_ + srow0 + lg*4] = s4;
            }
        }
    }
}

// ---------------- kernel A: denominators + ctx — in-lane PV, 16-q tile, b-inner grid ----------------
// Grid = 16 x 66 = 1056 blocks of 512 thr (wave = head): ~4 blocks/CU resident -> TLP
// hides L2 latency (R10's 528-block grid gave only 1 block/CU, 24.6% occupancy).
// b-inner keeps XCD L2 pinning (FETCH 25 MB, R10). In-lane PV: no LDS, no barriers.
#define CTX_TILE(KF, MV, VA, VB, PV0, PV1)                                        \
    {                                                                             \
        f32x4 acc = {0.f,0.f,0.f,0.f};                                            \
        acc = __builtin_amdgcn_mfma_f32_16x16x32_bf16(KF, qfrag, acc, 0, 0, 0);   \
        float e0 = __expf(acc[0]*bf2f(MV.x));                                     \
        float e1 = __expf(acc[1]*bf2f(MV.y));                                     \
        float e2 = __expf(acc[2]*bf2f(MV.z));                                     \
        float e3 = __expf(acc[3]*bf2f(MV.w));                                     \
        rssum += (e0+e1) + (e2+e3);                                               \
        bf16x4 pb; pb[0]=f2bf(e0); pb[1]=f2bf(e1); pb[2]=f2bf(e2); pb[3]=f2bf(e3);\
        PV0 = mfma16(pb, VA, PV0);                                                \
        PV1 = mfma16(pb, VB, PV1);                                                \
    }

__global__ __launch_bounds__(512, 4) void k_ctx(const short* __restrict__ Qb,
    const short* __restrict__ Kb, const short* __restrict__ VT,
    const short* __restrict__ maskb, short* __restrict__ ctxb, float* __restrict__ denomG)
{
    int tid  = threadIdx.x;
    int lane = tid & 63;
    int w    = tid >> 6;          // wave = head
    int b    = blockIdx.x & 15;   // b-inner: XCD pinning (b%8)
    int qt   = blockIdx.x >> 4;   // 0..65
    int q0   = qt * 16;
    int lr   = lane & 15;
    int lg   = lane >> 4;

    const int bh = b*H_ + w;
    bf16x8 qfrag = *(const bf16x8*)(Qb + ((size_t)bh*S_ + q0 + lr)*DK_ + lg*8);
    const short* Kp  = Kb + (size_t)bh*S_*DK_ + (size_t)lr*DK_ + lg*8;    // + k*DK_
    const short* Vp0 = VT + ((size_t)bh*DK_ + lr)*SP_ + 4*lg;             // d = lr
    const short* Vp1 = VT + ((size_t)bh*DK_ + 16 + lr)*SP_ + 4*lg;        // d = lr+16
    const short* Mp  = maskb + (size_t)(q0+lr)*S_ + 4*lg;

    // current-chunk registers (chunk 0)
    bf16x8 k0 = *(const bf16x8*)(Kp);
    bf16x8 k1 = *(const bf16x8*)(Kp + (size_t)16*DK_);
    ushort4 m0 = *(const ushort4*)(Mp);
    ushort4 m1 = *(const ushort4*)(Mp + 16);
    short4 v00 = *(const short4*)(Vp0);          // tile0, d-half0
    short4 v01 = *(const short4*)(Vp1);          // tile0, d-half1
    short4 v10 = *(const short4*)(Vp0 + 16);     // tile1, d-half0
    short4 v11 = *(const short4*)(Vp1 + 16);     // tile1, d-half1

    float rssum = 0.f;
    f32x4 pvA0 = {0.f,0.f,0.f,0.f}, pvA1 = {0.f,0.f,0.f,0.f};
    f32x4 pvB0 = {0.f,0.f,0.f,0.f}, pvB1 = {0.f,0.f,0.f,0.f};

    for (int u = 0; u < 32; ++u) {
        int kn = u*32 + 32;       // <= 1024: in-bounds, always consumed
        bf16x8 nk0 = *(const bf16x8*)(Kp + (size_t)kn*DK_);
        bf16x8 nk1 = *(const bf16x8*)(Kp + (size_t)(kn+16)*DK_);
        ushort4 nm0 = *(const ushort4*)(Mp + kn);
        ushort4 nm1 = *(const ushort4*)(Mp + kn + 16);
        short4 nv00 = *(const short4*)(Vp0 + kn);
        short4 nv01 = *(const short4*)(Vp1 + kn);
        short4 nv10 = *(const short4*)(Vp0 + kn + 16);
        short4 nv11 = *(const short4*)(Vp1 + kn + 16);

        CTX_TILE(k0, m0, *(const bf16x4*)&v00, *(const bf16x4*)&v01, pvA0, pvA1)
        CTX_TILE(k1, m1, *(const bf16x4*)&v10, *(const bf16x4*)&v11, pvB0, pvB1)

        k0 = nk0; k1 = nk1; m0 = nm0; m1 = nm1;
        v00 = nv00; v01 = nv01; v10 = nv10; v11 = nv11;
    }
    // peeled last chunk (k = 1024..1055)
    CTX_TILE(k0, m0, *(const bf16x4*)&v00, *(const bf16x4*)&v01, pvA0, pvA1)
    CTX_TILE(k1, m1, *(const bf16x4*)&v10, *(const bf16x4*)&v11, pvB0, pvB1)

    f32x4 pv0, pv1;
    pv0[0]=pvA0[0]+pvB0[0]; pv0[1]=pvA0[1]+pvB0[1]; pv0[2]=pvA0[2]+pvB0[2]; pv0[3]=pvA0[3]+pvB0[3];
    pv1[0]=pvA1[0]+pvB1[0]; pv1[1]=pvA1[1]+pvB1[1]; pv1[2]=pvA1[2]+pvB1[2]; pv1[3]=pvA1[3]+pvB1[3];

    // row sums: lane (lr,lg) holds partial for q=lr; reduce over lg
    rssum += __shfl_xor(rssum, 16, 64);
    rssum += __shfl_xor(rssum, 32, 64);
    float rd = 1.f / rssum;
    if (lane < 16)
        denomG[(size_t)bh*S_ + q0 + lane] = rd;

    // pv[r] = ctx[q=4lg+r][d=lr (pv0) / lr+16 (pv1)]
    #pragma unroll
    for (int r = 0; r < 4; ++r) {
        float rdq = __shfl(rd, 4*lg + r, 64);
        size_t off = ((size_t)b*S_ + q0 + 4*lg + r)*DM_ + w*DK_ + lr;
        ctxb[off]      = f2bf(pv0[r] * rdq);
        ctxb[off + 16] = f2bf(pv1[r] * rdq);
    }
}

// ---------------- kernel B: att by score recompute (b-inner grid) ----------------
__global__ __launch_bounds__(256, 4) void k_att(const short* __restrict__ Qb,
    const short* __restrict__ Kb, const short* __restrict__ maskb,
    const float* __restrict__ denomG, float* __restrict__ att)
{
    __shared__ float rd_l[8][16];
    int tid  = threadIdx.x;
    int lane = tid & 63;
    int w    = tid >> 6;
    int b    = blockIdx.x & 15;       // b-inner: XCD pinning
    int qt   = blockIdx.x >> 4;
    int q0   = qt * 16;

    if (tid < 128)
        rd_l[tid>>4][tid&15] = denomG[(size_t)(b*H_+(tid>>4))*S_ + q0 + (tid&15)] * 0.125f;
    __syncthreads();

    int lr = lane & 15;
    int lg = lane >> 4;

    bf16x8 qf[8];
    #pragma unroll
    for (int h = 0; h < 8; ++h)
        qf[h] = *(const bf16x8*)(Qb + ((size_t)(b*H_+h)*S_ + q0+lr)*DK_ + lg*8);

    const size_t kstride = (size_t)S_*DK_;
    const short* Kbase = Kb + (size_t)b*H_*kstride + lg*8;

    int nt = (w < 2) ? 17 : 16;
    for (int t = 0; t < nt; ++t) {
        int k0 = t*64 + w*16;
        bf16x8 kf[8];
        #pragma unroll
        for (int h = 0; h < 8; ++h)
            kf[h] = *(const bf16x8*)(Kbase + (size_t)h*kstride + (size_t)(k0+lr)*DK_);
        float m0 = bf2f((unsigned short)maskb[(size_t)(q0+4*lg+0)*S_ + k0+lr]);
        float m1 = bf2f((unsigned short)maskb[(size_t)(q0+4*lg+1)*S_ + k0+lr]);
        float m2 = bf2f((unsigned short)maskb[(size_t)(q0+4*lg+2)*S_ + k0+lr]);
        float m3 = bf2f((unsigned short)maskb[(size_t)(q0+4*lg+3)*S_ + k0+lr]);
        f32x4 a = {0.f,0.f,0.f,0.f};
        #pragma unroll
        for (int h = 0; h < 8; ++h) {
            f32x4 s = {0.f,0.f,0.f,0.f};
            s = __builtin_amdgcn_mfma_f32_16x16x32_bf16(qf[h], kf[h], s, 0, 0, 0);
            a[0] = fmaf(__expf(s[0]*m0), rd_l[h][4*lg+0], a[0]);
            a[1] = fmaf(__expf(s[1]*m1), rd_l[h][4*lg+1], a[1]);
            a[2] = fmaf(__expf(s[2]*m2), rd_l[h][4*lg+2], a[2]);
            a[3] = fmaf(__expf(s[3]*m3), rd_l[h][4*lg+3], a[3]);
        }
        att[((size_t)b*S_ + q0+4*lg+0)*S_ + k0+lr] = a[0];
        att[((size_t)b*S_ + q0+4*lg+1)*S_ + k0+lr] = a[1];
        att[((size_t)b*S_ + q0+4*lg+2)*S_ + k0+lr] = a[2];
        att[((size_t)b*S_ + q0+4*lg+3)*S_ + k0+lr] = a[3];
    }
}

// ---------------- out projection via MFMA (no LDS) ----------------
__global__ __launch_bounds__(256, 2) void k_outproj(const short* __restrict__ ctxb,
    const short* __restrict__ WoB, const float* __restrict__ bias, float* __restrict__ out)
{
    int tid  = threadIdx.x;
    int lane = tid & 63;
    int w    = tid >> 6;
    int lr   = lane & 15;
    int lg   = lane >> 4;
    int r0   = blockIdx.x * 16;

    bf16x8 cf[8];
    #pragma unroll
    for (int kk = 0; kk < 8; ++kk)
        cf[kk] = *(const bf16x8*)(ctxb + (size_t)(r0+lr)*DM_ + kk*32 + lg*8);

    #pragma unroll
    for (int ct = 0; ct < 4; ++ct) {
        int tb = (w + ct*4) * 16;
        const short* Wp = WoB + (size_t)(tb+lr)*DM_ + lg*8;
        f32x4 acc = {0.f,0.f,0.f,0.f};
        #pragma unroll
        for (int kk = 0; kk < 8; ++kk) {
            bf16x8 wf = *(const bf16x8*)(Wp + kk*32);
            acc = __builtin_amdgcn_mfma_f32_16x16x32_bf16(wf, cf[kk], acc, 0, 0, 0);
        }
        float4 b4 = *(const float4*)&bias[tb + lg*4];
        float4 o4 = make_float4(acc[0]+b4.x, acc[1]+b4.y, acc[2]+b4.z, acc[3]+b4.w);
        *(float4*)&out[(size_t)(r0+lr)*DM_ + tb + lg*4] = o4;
    }
}

extern "C" void kernel_launch(void* const* d_in, const int* in_sizes, int n_in,
                              void* d_out, int out_size, void* d_ws, size_t ws_size,
                              hipStream_t stream)
{
    (void)in_sizes; (void)n_in; (void)out_size; (void)ws_size;
    const float* src  = (const float*)d_in[0];
    const float* Wtq  = (const float*)d_in[1];
    const float* Wtk  = (const float*)d_in[2];
    const float* Wtv  = (const float*)d_in[3];
    const float* Wvq  = (const float*)d_in[4];
    const float* Wvk  = (const float*)d_in[5];
    const float* Wvv  = (const float*)d_in[6];
    const float* lvr  = (const float*)d_in[7];
    const float* Wout = (const float*)d_in[8];
    const float* bout = (const float*)d_in[9];
    const int*   rid  = (const int*)d_in[10];
    const int*   cid  = (const int*)d_in[11];

    const size_t QKV_SH = (size_t)B_*H_*S_*DK_;    // shorts per Q/K buffer
    const size_t VT_SH  = (size_t)B_*H_*DK_*SP_;   // shorts for V^T
    const size_t CTX_SH = (size_t)B_*S_*DM_;

    float* ws       = (float*)d_ws;
    float* partials = ws;                           // 4356
    float* denomG   = partials + 4356;              // B*H*S
    short* maskb    = (short*)(denomG + (size_t)B_*H_*S_);
    short* Qb       = maskb + SS_;
    short* Kb       = Qb + QKV_SH;
    short* VT       = Kb + QKV_SH;
    short* ctxb     = VT + VT_SH;
    short* WTall    = ctxb + CTX_SH;                // 6*65536
    short* WoB      = WTall + 6*65536;

    float* out  = (float*)d_out;
    float* att  = out + (size_t)B_*S_*DM_;
    float* loss = att + (size_t)B_*S_*S_;

    k_mask<<<SS_/256, 256, 0, stream>>>(lvr, rid, cid, maskb, partials);
    k_wprep<<<7*256, 256, 0, stream>>>(Wtq, Wtk, Wtv, Wvq, Wvk, Wvv, Wout, WTall, WoB);
    k_qkv<<<(B_*TXT_)/16, 256, 0, stream>>>(src, WTall, WTall+65536, WTall+2*65536,
                                            Qb, Kb, VT, 1);
    k_qkv<<<(B_*VID_)/16, 256, 0, stream>>>(src, WTall+3*65536, WTall+4*65536, WTall+5*65536,
                                            Qb, Kb, VT, 0);
    k_ctx<<<B_*NQT_, 512, 0, stream>>>(Qb, Kb, VT, maskb, ctxb, denomG);
    k_att<<<B_*NQT_, 256, 0, stream>>>(Qb, Kb, maskb, denomG, att);
    k_outproj<<<(B_*S_)/16, 256, 0, stream>>>(ctxb, WoB, bout, out);
    k_loss<<<1, 256, 0, stream>>>(partials, loss);
}

// Round 12
// 387.145 us; speedup vs baseline: 1.0004x; 1.0004x over previous
//
#include <hip/hip_runtime.h>
#include <math.h>

#define B_   16
#define S_   1056
#define SP_  1088             // k padded to 34*32
#define DM_  256
#define H_   8
#define DK_  32
#define TXT_ 32
#define VID_ 1024
#define SS_  (S_*S_)          // 1115136
#define NQT_ 66               // q-tiles of 16 rows

#define LOG2_10000f 13.28771237954945f
#define LOG2_GAMMAf (-0.15200309344504995f)   // log2(0.9)
#define RSQRT_DKf   0.17677669529663687f      // 1/sqrt(32)
#define TWO_PIf     6.283185307179586f

typedef __attribute__((ext_vector_type(8))) short bf16x8;
typedef __attribute__((ext_vector_type(4))) short bf16x4;
typedef __attribute__((ext_vector_type(4))) float f32x4;

__device__ __forceinline__ short f2bf(float f){
    unsigned u = __float_as_uint(f);
    unsigned r = u + 0x7FFFu + ((u >> 16) & 1u);   // RNE
    return (short)(r >> 16);
}
__device__ __forceinline__ float bf2f(unsigned short s){
    return __uint_as_float(((unsigned)s) << 16);
}

// K=16 bf16 MFMA: A-frag lane(lr,lg) holds A[row=lr][k=4lg+j] — exactly the
// D-layout of the QK^T tile (P[q=lr][k=4lg+r]), so P feeds PV in-lane.
__device__ __forceinline__ f32x4 mfma16(bf16x4 a, bf16x4 b, f32x4 c){
#if __has_builtin(__builtin_amdgcn_mfma_f32_16x16x16bf16_1k)
    return __builtin_amdgcn_mfma_f32_16x16x16bf16_1k(a, b, c, 0, 0, 0);
#else
    f32x4 d = c;
    asm("v_mfma_f32_16x16x16_bf16 %0, %1, %2, %0" : "+v"(d) : "v"(a), "v"(b));
    return d;
#endif
}

// ---------------- mask (bf16) + loss partials ----------------
__global__ __launch_bounds__(256) void k_mask(const float* __restrict__ lvr,
                       const int* __restrict__ row_idx, const int* __restrict__ col_idx,
                       short* __restrict__ maskb, float* __restrict__ partials)
{
    int idx = blockIdx.x*256 + threadIdx.x;
    unsigned ui = (unsigned)idx;
    int i = ui / S_;
    int j = (int)(ui - (unsigned)i*S_);
    float vr, lm;
    if (i == j) { vr = 0.f; lm = 1.f; }
    else {
        float t = lvr[(size_t)row_idx[idx]*VID_ + col_idx[idx]];
        float sg = 1.f/(1.f + expf(-t));
        vr = sg; lm = sg;
    }
    float dmat = (i >= j) ? exp2f((float)(i-j)*LOG2_GAMMAf) : 0.f;
    maskb[idx] = f2bf(dmat * lm);
    float s = vr;
    #pragma unroll
    for (int m=1; m<64; m<<=1) s += __shfl_xor(s, m, 64);
    __shared__ float ws4[4];
    if ((threadIdx.x & 63) == 0) ws4[threadIdx.x>>6] = s;
    __syncthreads();
    if (threadIdx.x == 0) partials[blockIdx.x] = ws4[0]+ws4[1]+ws4[2]+ws4[3];
}

__global__ __launch_bounds__(256) void k_loss(const float* __restrict__ partials,
                                              float* __restrict__ out_loss)
{
    float s = 0.f;
    for (int i = threadIdx.x; i < SS_/256; i += 256) s += partials[i];
    #pragma unroll
    for (int m=1; m<64; m<<=1) s += __shfl_xor(s, m, 64);
    __shared__ float ws4[4];
    if ((threadIdx.x & 63) == 0) ws4[threadIdx.x>>6] = s;
    __syncthreads();
    if (threadIdx.x == 0) out_loss[0] = (ws4[0]+ws4[1]+ws4[2]+ws4[3]) * (1.f/(float)SS_);
}

// ---------------- weight prep ----------------
__global__ __launch_bounds__(256) void k_wprep(
    const float* __restrict__ Wtq, const float* __restrict__ Wtk, const float* __restrict__ Wtv,
    const float* __restrict__ Wvq, const float* __restrict__ Wvk, const float* __restrict__ Wvv,
    const float* __restrict__ Wout, short* __restrict__ WTall, short* __restrict__ WoB)
{
    int seg = blockIdx.x >> 8;
    int r   = blockIdx.x & 255;
    int tid = threadIdx.x;
    if (seg == 6) {
        WoB[r*256 + tid] = f2bf(Wout[r*256 + tid]);
    } else {
        const float* Wsrc = seg==0?Wtq: seg==1?Wtk: seg==2?Wtv: seg==3?Wvq: seg==4?Wvk: Wvv;
        WTall[(size_t)seg*65536 + r*256 + tid] = f2bf(Wsrc[tid*256 + r]);
    }
}

// ---------------- QKV projection via MFMA (unchanged, passing) ----------------
__global__ __launch_bounds__(256, 2) void k_qkv(const float* __restrict__ src,
    const short* __restrict__ WTq, const short* __restrict__ WTk, const short* __restrict__ WTv,
    short* __restrict__ Qb, short* __restrict__ Kb, short* __restrict__ VT, int is_txt)
{
    __shared__ __align__(16) short xb[3][16][256];   // 24 KB
    __shared__ float invf[128];
    __shared__ float lbs[128];
    int tid = threadIdx.x;
    int r0 = blockIdx.x * 16;
    int b, srow0;
    if (is_txt) { b = r0 >> 5;  srow0 = r0 & 31; }
    else        { b = r0 >> 10; srow0 = TXT_ + (r0 & 1023); }

    if (tid < 128) {
        float fk = (float)tid;
        invf[tid] = exp2f(-fk*(1.f/128.f)*LOG2_10000f);
        lbs[tid]  = log2f((2.f*fk + 102.4f) * (1.f/358.4f));
    }
    __syncthreads();

    #pragma unroll
    for (int it = 0; it < 8; ++it) {
        int task = it*256 + tid;
        int k  = task >> 4;
        int rr = task & 15;
        int srow = srow0 + rr;
        float2 x01 = ((const float2*)(src + ((size_t)b*S_ + srow)*DM_))[k];
        float a0, a1, c0, c1;
        if (is_txt) {
            float xe  = (float)(srow + 1) * (TWO_PIf/(32.f + 1e-6f));
            float arg = xe * invf[k];
            float sn = __sinf(arg), cs = __cosf(arg);
            a0 = x01.x + sn; a1 = x01.y + cs;
            c0 = a0; c1 = a1;
        } else {
            int l = srow - TXT_;
            float arg = (float)l * invf[k];
            float sn = __sinf(arg), cs = __cosf(arg);
            float scale = exp2f((float)l*(1.f/512.f)*lbs[k]);
            float rsc = 1.f/scale;
            float y0 = x01.x*cs - x01.y*sn;
            float y1 = x01.y*cs + x01.x*sn;
            a0 = y0*scale; a1 = y1*scale;
            c0 = y0*rsc;   c1 = y1*rsc;
        }
        int col = (2*k) ^ ((rr&7)<<3);
        *(short2*)&xb[0][rr][col] = make_short2(f2bf(a0), f2bf(a1));
        *(short2*)&xb[1][rr][col] = make_short2(f2bf(c0), f2bf(c1));
        *(short2*)&xb[2][rr][col] = make_short2(f2bf(x01.x), f2bf(x01.y));
    }
    __syncthreads();

    int lane = tid & 63;
    int w    = tid >> 6;
    int lr   = lane & 15;
    int lg   = lane >> 4;
    int swzl = (lr & 7) << 3;

    const short* WTs[3] = {WTq, WTk, WTv};
    #pragma unroll
    for (int m = 0; m < 3; ++m) {
        bf16x8 xf[8];
        #pragma unroll
        for (int kk = 0; kk < 8; ++kk)
            xf[kk] = *(const bf16x8*)&xb[m][lr][(kk*32 + lg*8) ^ swzl];
        #pragma unroll
        for (int ct = 0; ct < 4; ++ct) {
            int tb = (w + ct*4) * 16;
            const short* Wp = WTs[m] + (size_t)(tb+lr)*DM_ + lg*8;
            f32x4 acc = {0.f,0.f,0.f,0.f};
            if (m < 2) {
                #pragma unroll
                for (int kk = 0; kk < 8; ++kk) {
                    bf16x8 wf = *(const bf16x8*)(Wp + kk*32);
                    acc = __builtin_amdgcn_mfma_f32_16x16x32_bf16(wf, xf[kk], acc, 0, 0, 0);
                }
                int h  = tb >> 5;
                int d0 = (tb & 31) + lg*4;
                size_t off = ((size_t)(b*H_+h)*S_ + srow0+lr)*DK_ + d0;
                short4 s4;
                if (m == 0) {
                    s4.x=f2bf(acc[0]*RSQRT_DKf); s4.y=f2bf(acc[1]*RSQRT_DKf);
                    s4.z=f2bf(acc[2]*RSQRT_DKf); s4.w=f2bf(acc[3]*RSQRT_DKf);
                    *(short4*)&Qb[off] = s4;
                } else {
                    s4.x=f2bf(acc[0]); s4.y=f2bf(acc[1]);
                    s4.z=f2bf(acc[2]); s4.w=f2bf(acc[3]);
                    *(short4*)&Kb[off] = s4;
                }
            } else {
                #pragma unroll
                for (int kk = 0; kk < 8; ++kk) {
                    bf16x8 wf = *(const bf16x8*)(Wp + kk*32);
                    acc = __builtin_amdgcn_mfma_f32_16x16x32_bf16(xf[kk], wf, acc, 0, 0, 0);
                }
                int o = tb + lr;
                int h = o >> 5, d = o & 31;
                short4 s4;
                s4.x=f2bf(acc[0]); s4.y=f2bf(acc[1]);
                s4.z=f2bf(acc[2]); s4.w=f2bf(acc[3]);
                *(short4*)&VT[((size_t)(b*H_+h)*DK_ + d)*SP_ + srow0 + lg*4] = s4;
            }
        }
    }
}

// ---------------- kernel A: denominators + ctx — in-lane PV, intra-iteration batching ----------------
// k_att-style load batching: per group of 3 chunks (96 k; 33 = 11x3, no tail),
// issue 24 independent loads (6 K-frags, 6 mask quads, 12 V short4) BEFORE the
// compute of the same iteration. Nothing (except accumulators) lives across the
// backedge -> compiler can't sink the batch; one latency exposure per 96 k.
#define CTX_TILE(KF, MV, VA, VB, PV0, PV1)                                        \
    {                                                                             \
        f32x4 acc = {0.f,0.f,0.f,0.f};                                            \
        acc = __builtin_amdgcn_mfma_f32_16x16x32_bf16(KF, qfrag, acc, 0, 0, 0);   \
        float e0 = __expf(acc[0]*bf2f(MV.x));                                     \
        float e1 = __expf(acc[1]*bf2f(MV.y));                                     \
        float e2 = __expf(acc[2]*bf2f(MV.z));                                     \
        float e3 = __expf(acc[3]*bf2f(MV.w));                                     \
        rssum += (e0+e1) + (e2+e3);                                               \
        bf16x4 pb; pb[0]=f2bf(e0); pb[1]=f2bf(e1); pb[2]=f2bf(e2); pb[3]=f2bf(e3);\
        PV0 = mfma16(pb, VA, PV0);                                                \
        PV1 = mfma16(pb, VB, PV1);                                                \
    }

__global__ __launch_bounds__(512, 2) void k_ctx(const short* __restrict__ Qb,
    const short* __restrict__ Kb, const short* __restrict__ VT,
    const short* __restrict__ maskb, short* __restrict__ ctxb, float* __restrict__ denomG)
{
    int tid  = threadIdx.x;
    int lane = tid & 63;
    int w    = tid >> 6;          // wave = head
    int b    = blockIdx.x & 15;   // b-inner: XCD pinning (b%8)
    int qt   = blockIdx.x >> 4;   // 0..65
    int q0   = qt * 16;
    int lr   = lane & 15;
    int lg   = lane >> 4;

    const int bh = b*H_ + w;
    bf16x8 qfrag = *(const bf16x8*)(Qb + ((size_t)bh*S_ + q0 + lr)*DK_ + lg*8);
    const short* Kp  = Kb + (size_t)bh*S_*DK_ + (size_t)lr*DK_ + lg*8;    // + k*DK_
    const short* Vp0 = VT + ((size_t)bh*DK_ + lr)*SP_ + 4*lg;             // d = lr
    const short* Vp1 = VT + ((size_t)bh*DK_ + 16 + lr)*SP_ + 4*lg;        // d = lr+16
    const short* Mp  = maskb + (size_t)(q0+lr)*S_ + 4*lg;

    float rssum = 0.f;
    f32x4 pvA0 = {0.f,0.f,0.f,0.f}, pvA1 = {0.f,0.f,0.f,0.f};
    f32x4 pvB0 = {0.f,0.f,0.f,0.f}, pvB1 = {0.f,0.f,0.f,0.f};

    for (int g = 0; g < 11; ++g) {
        int kb = g * 96;
        // ---- load batch: 24 independent loads, all used below in this iteration ----
        bf16x8 K[6]; ushort4 M[6]; short4 V[12];
        #pragma unroll
        for (int c = 0; c < 3; ++c) {
            int k0 = kb + c*32;
            K[2*c]   = *(const bf16x8*)(Kp + (size_t)k0*DK_);
            K[2*c+1] = *(const bf16x8*)(Kp + (size_t)(k0+16)*DK_);
            M[2*c]   = *(const ushort4*)(Mp + k0);
            M[2*c+1] = *(const ushort4*)(Mp + k0 + 16);
            V[4*c+0] = *(const short4*)(Vp0 + k0);
            V[4*c+1] = *(const short4*)(Vp1 + k0);
            V[4*c+2] = *(const short4*)(Vp0 + k0 + 16);
            V[4*c+3] = *(const short4*)(Vp1 + k0 + 16);
        }
        // ---- compute 3 chunks (6 tiles) ----
        #pragma unroll
        for (int c = 0; c < 3; ++c) {
            CTX_TILE(K[2*c],   M[2*c],   *(const bf16x4*)&V[4*c+0], *(const bf16x4*)&V[4*c+1], pvA0, pvA1)
            CTX_TILE(K[2*c+1], M[2*c+1], *(const bf16x4*)&V[4*c+2], *(const bf16x4*)&V[4*c+3], pvB0, pvB1)
        }
    }

    f32x4 pv0, pv1;
    pv0[0]=pvA0[0]+pvB0[0]; pv0[1]=pvA0[1]+pvB0[1]; pv0[2]=pvA0[2]+pvB0[2]; pv0[3]=pvA0[3]+pvB0[3];
    pv1[0]=pvA1[0]+pvB1[0]; pv1[1]=pvA1[1]+pvB1[1]; pv1[2]=pvA1[2]+pvB1[2]; pv1[3]=pvA1[3]+pvB1[3];

    // row sums: lane (lr,lg) holds partial for q=lr; reduce over lg
    rssum += __shfl_xor(rssum, 16, 64);
    rssum += __shfl_xor(rssum, 32, 64);
    float rd = 1.f / rssum;
    if (lane < 16)
        denomG[(size_t)bh*S_ + q0 + lane] = rd;

    // pv[r] = ctx[q=4lg+r][d=lr (pv0) / lr+16 (pv1)]
    #pragma unroll
    for (int r = 0; r < 4; ++r) {
        float rdq = __shfl(rd, 4*lg + r, 64);
        size_t off = ((size_t)b*S_ + q0 + 4*lg + r)*DM_ + w*DK_ + lr;
        ctxb[off]      = f2bf(pv0[r] * rdq);
        ctxb[off + 16] = f2bf(pv1[r] * rdq);
    }
}

// ---------------- kernel B: att by score recompute (b-inner grid) ----------------
__global__ __launch_bounds__(256, 4) void k_att(const short* __restrict__ Qb,
    const short* __restrict__ Kb, const short* __restrict__ maskb,
    const float* __restrict__ denomG, float* __restrict__ att)
{
    __shared__ float rd_l[8][16];
    int tid  = threadIdx.x;
    int lane = tid & 63;
    int w    = tid >> 6;
    int b    = blockIdx.x & 15;       // b-inner: XCD pinning
    int qt   = blockIdx.x >> 4;
    int q0   = qt * 16;

    if (tid < 128)
        rd_l[tid>>4][tid&15] = denomG[(size_t)(b*H_+(tid>>4))*S_ + q0 + (tid&15)] * 0.125f;
    __syncthreads();

    int lr = lane & 15;
    int lg = lane >> 4;

    bf16x8 qf[8];
    #pragma unroll
    for (int h = 0; h < 8; ++h)
        qf[h] = *(const bf16x8*)(Qb + ((size_t)(b*H_+h)*S_ + q0+lr)*DK_ + lg*8);

    const size_t kstride = (size_t)S_*DK_;
    const short* Kbase = Kb + (size_t)b*H_*kstride + lg*8;

    int nt = (w < 2) ? 17 : 16;
    for (int t = 0; t < nt; ++t) {
        int k0 = t*64 + w*16;
        bf16x8 kf[8];
        #pragma unroll
        for (int h = 0; h < 8; ++h)
            kf[h] = *(const bf16x8*)(Kbase + (size_t)h*kstride + (size_t)(k0+lr)*DK_);
        float m0 = bf2f((unsigned short)maskb[(size_t)(q0+4*lg+0)*S_ + k0+lr]);
        float m1 = bf2f((unsigned short)maskb[(size_t)(q0+4*lg+1)*S_ + k0+lr]);
        float m2 = bf2f((unsigned short)maskb[(size_t)(q0+4*lg+2)*S_ + k0+lr]);
        float m3 = bf2f((unsigned short)maskb[(size_t)(q0+4*lg+3)*S_ + k0+lr]);
        f32x4 a = {0.f,0.f,0.f,0.f};
        #pragma unroll
        for (int h = 0; h < 8; ++h) {
            f32x4 s = {0.f,0.f,0.f,0.f};
            s = __builtin_amdgcn_mfma_f32_16x16x32_bf16(qf[h], kf[h], s, 0, 0, 0);
            a[0] = fmaf(__expf(s[0]*m0), rd_l[h][4*lg+0], a[0]);
            a[1] = fmaf(__expf(s[1]*m1), rd_l[h][4*lg+1], a[1]);
            a[2] = fmaf(__expf(s[2]*m2), rd_l[h][4*lg+2], a[2]);
            a[3] = fmaf(__expf(s[3]*m3), rd_l[h][4*lg+3], a[3]);
        }
        att[((size_t)b*S_ + q0+4*lg+0)*S_ + k0+lr] = a[0];
        att[((size_t)b*S_ + q0+4*lg+1)*S_ + k0+lr] = a[1];
        att[((size_t)b*S_ + q0+4*lg+2)*S_ + k0+lr] = a[2];
        att[((size_t)b*S_ + q0+4*lg+3)*S_ + k0+lr] = a[3];
    }
}

// ---------------- out projection via MFMA (no LDS) ----------------
__global__ __launch_bounds__(256, 2) void k_outproj(const short* __restrict__ ctxb,
    const short* __restrict__ WoB, const float* __restrict__ bias, float* __restrict__ out)
{
    int tid  = threadIdx.x;
    int lane = tid & 63;
    int w    = tid >> 6;
    int lr   = lane & 15;
    int lg   = lane >> 4;
    int r0   = blockIdx.x * 16;

    bf16x8 cf[8];
    #pragma unroll
    for (int kk = 0; kk < 8; ++kk)
        cf[kk] = *(const bf16x8*)(ctxb + (size_t)(r0+lr)*DM_ + kk*32 + lg*8);

    #pragma unroll
    for (int ct = 0; ct < 4; ++ct) {
        int tb = (w + ct*4) * 16;
        const short* Wp = WoB + (size_t)(tb+lr)*DM_ + lg*8;
        f32x4 acc = {0.f,0.f,0.f,0.f};
        #pragma unroll
        for (int kk = 0; kk < 8; ++kk) {
            bf16x8 wf = *(const bf16x8*)(Wp + kk*32);
            acc = __builtin_amdgcn_mfma_f32_16x16x32_bf16(wf, cf[kk], acc, 0, 0, 0);
        }
        float4 b4 = *(const float4*)&bias[tb + lg*4];
        float4 o4 = make_float4(acc[0]+b4.x, acc[1]+b4.y, acc[2]+b4.z, acc[3]+b4.w);
        *(float4*)&out[(size_t)(r0+lr)*DM_ + tb + lg*4] = o4;
    }
}

extern "C" void kernel_launch(void* const* d_in, const int* in_sizes, int n_in,
                              void* d_out, int out_size, void* d_ws, size_t ws_size,
                              hipStream_t stream)
{
    (void)in_sizes; (void)n_in; (void)out_size; (void)ws_size;
    const float* src  = (const float*)d_in[0];
    const float* Wtq  = (const float*)d_in[1];
    const float* Wtk  = (const float*)d_in[2];
    const float* Wtv  = (const float*)d_in[3];
    const float* Wvq  = (const float*)d_in[4];
    const float* Wvk  = (const float*)d_in[5];
    const float* Wvv  = (const float*)d_in[6];
    const float* lvr  = (const float*)d_in[7];
    const float* Wout = (const float*)d_in[8];
    const float* bout = (const float*)d_in[9];
    const int*   rid  = (const int*)d_in[10];
    const int*   cid  = (const int*)d_in[11];

    const size_t QKV_SH = (size_t)B_*H_*S_*DK_;    // shorts per Q/K buffer
    const size_t VT_SH  = (size_t)B_*H_*DK_*SP_;   // shorts for V^T
    const size_t CTX_SH = (size_t)B_*S_*DM_;

    float* ws       = (float*)d_ws;
    float* partials = ws;                           // 4356
    float* denomG   = partials + 4356;              // B*H*S
    short* maskb    = (short*)(denomG + (size_t)B_*H_*S_);
    short* Qb       = maskb + SS_;
    short* Kb       = Qb + QKV_SH;
    short* VT       = Kb + QKV_SH;
    short* ctxb     = VT + VT_SH;
    short* WTall    = ctxb + CTX_SH;                // 6*65536
    short* WoB      = WTall + 6*65536;

    float* out  = (float*)d_out;
    float* att  = out + (size_t)B_*S_*DM_;
    float* loss = att + (size_t)B_*S_*S_;

    k_mask<<<SS_/256, 256, 0, stream>>>(lvr, rid, cid, maskb, partials);
    k_wprep<<<7*256, 256, 0, stream>>>(Wtq, Wtk, Wtv, Wvq, Wvk, Wvv, Wout, WTall, WoB);
    k_qkv<<<(B_*TXT_)/16, 256, 0, stream>>>(src, WTall, WTall+65536, WTall+2*65536,
                                            Qb, Kb, VT, 1);
    k_qkv<<<(B_*VID_)/16, 256, 0, stream>>>(src, WTall+3*65536, WTall+4*65536, WTall+5*65536,
                                            Qb, Kb, VT, 0);
    k_ctx<<<B_*NQT_, 512, 0, stream>>>(Qb, Kb, VT, maskb, ctxb, denomG);
    k_att<<<B_*NQT_, 256, 0, stream>>>(Qb, Kb, maskb, denomG, att);
    k_outproj<<<(B_*S_)/16, 256, 0, stream>>>(ctxb, WoB, bout, out);
    k_loss<<<1, 256, 0, stream>>>(partials, loss);
}

// Round 13
// 238.111 us; speedup vs baseline: 1.6266x; 1.6259x over previous
//
#include <hip/hip_runtime.h>
#include <math.h>

#define B_   16
#define S_   1056
#define DM_  256
#define H_   8
#define DK_  32
#define TXT_ 32
#define VID_ 1024
#define SS_  (S_*S_)          // 1115136
#define NQT_ 66               // q-tiles of 16 rows
#define NKT_ 66               // k-tiles of 16
#define MASK_BLKS 1089        // (66*66*64)/256

#define LOG2_10000f 13.28771237954945f
#define LOG2_GAMMAf (-0.15200309344504995f)   // log2(0.9)
#define RSQRT_DKf   0.17677669529663687f      // 1/sqrt(32)
#define TWO_PIf     6.283185307179586f

typedef __attribute__((ext_vector_type(8))) short bf16x8;
typedef __attribute__((ext_vector_type(4))) short bf16x4;
typedef __attribute__((ext_vector_type(4))) float f32x4;

__device__ __forceinline__ short f2bf(float f){
    unsigned u = __float_as_uint(f);
    unsigned r = u + 0x7FFFu + ((u >> 16) & 1u);   // RNE
    return (short)(r >> 16);
}
__device__ __forceinline__ float bf2f(unsigned short s){
    return __uint_as_float(((unsigned)s) << 16);
}

// K=16 bf16 MFMA: A-frag lane l holds A[row=l%16][k=4(l/16)+j] — exactly the
// D-layout of the QK^T tile, so P feeds PV in-lane.
__device__ __forceinline__ f32x4 mfma16(bf16x4 a, bf16x4 b, f32x4 c){
#if __has_builtin(__builtin_amdgcn_mfma_f32_16x16x16bf16_1k)
    return __builtin_amdgcn_mfma_f32_16x16x16bf16_1k(a, b, c, 0, 0, 0);
#else
    f32x4 d = c;
    asm("v_mfma_f32_16x16x16_bf16 %0, %1, %2, %0" : "+v"(d) : "v"(a), "v"(b));
    return d;
#endif
}

// ---------------- mask: fragment-order maskf + row-major maskb + loss partials ----------------
// Thread T -> (qt,kt,l): computes 4 mask elems (q = qt*16 + l%16, k = kt*16 + 4*(l/16)+j).
// maskf[(qt*66+kt)*256 + l*4] is the P-fragment layout used by k_ctx (coalesced 512B/tile).
__global__ __launch_bounds__(256) void k_mask(const float* __restrict__ lvr,
                       const int* __restrict__ row_idx, const int* __restrict__ col_idx,
                       short* __restrict__ maskf, short* __restrict__ maskb,
                       float* __restrict__ partials)
{
    int T  = blockIdx.x*256 + threadIdx.x;
    int l  = T & 63;
    int qk = T >> 6;                  // qt*66 + kt
    int qt = qk / 66;
    int kt = qk - qt*66;
    int i  = qt*16 + (l & 15);
    int j0 = kt*16 + 4*(l >> 4);
    size_t idx = (size_t)i*S_ + j0;   // 4-aligned (S_%4==0, j0%4==0)
    int4 ri4 = *(const int4*)&row_idx[idx];
    int4 ci4 = *(const int4*)&col_idx[idx];
    int rr[4] = {ri4.x, ri4.y, ri4.z, ri4.w};
    int cc[4] = {ci4.x, ci4.y, ci4.z, ci4.w};
    float vrs = 0.f;
    short4 mq;
    short* mp = (short*)&mq;
    #pragma unroll
    for (int jj = 0; jj < 4; ++jj) {
        int j = j0 + jj;
        float vr, lm;
        if (i == j) { vr = 0.f; lm = 1.f; }
        else {
            float t = lvr[(size_t)rr[jj]*VID_ + cc[jj]];
            float sg = 1.f/(1.f + expf(-t));
            vr = sg; lm = sg;
        }
        float dmat = (i >= j) ? exp2f((float)(i-j)*LOG2_GAMMAf) : 0.f;
        mp[jj] = f2bf(dmat * lm);
        vrs += vr;
    }
    *(short4*)&maskb[idx] = mq;
    *(short4*)&maskf[(size_t)qk*256 + l*4] = mq;

    float s = vrs;
    #pragma unroll
    for (int m=1; m<64; m<<=1) s += __shfl_xor(s, m, 64);
    __shared__ float ws4[4];
    if ((threadIdx.x & 63) == 0) ws4[threadIdx.x>>6] = s;
    __syncthreads();
    if (threadIdx.x == 0) partials[blockIdx.x] = ws4[0]+ws4[1]+ws4[2]+ws4[3];
}

__global__ __launch_bounds__(256) void k_loss(const float* __restrict__ partials,
                                              float* __restrict__ out_loss)
{
    float s = 0.f;
    for (int i = threadIdx.x; i < MASK_BLKS; i += 256) s += partials[i];
    #pragma unroll
    for (int m=1; m<64; m<<=1) s += __shfl_xor(s, m, 64);
    __shared__ float ws4[4];
    if ((threadIdx.x & 63) == 0) ws4[threadIdx.x>>6] = s;
    __syncthreads();
    if (threadIdx.x == 0) out_loss[0] = (ws4[0]+ws4[1]+ws4[2]+ws4[3]) * (1.f/(float)SS_);
}

// ---------------- weight prep ----------------
__global__ __launch_bounds__(256) void k_wprep(
    const float* __restrict__ Wtq, const float* __restrict__ Wtk, const float* __restrict__ Wtv,
    const float* __restrict__ Wvq, const float* __restrict__ Wvk, const float* __restrict__ Wvv,
    const float* __restrict__ Wout, short* __restrict__ WTall, short* __restrict__ WoB)
{
    int seg = blockIdx.x >> 8;
    int r   = blockIdx.x & 255;
    int tid = threadIdx.x;
    if (seg == 6) {
        WoB[r*256 + tid] = f2bf(Wout[r*256 + tid]);
    } else {
        const float* Wsrc = seg==0?Wtq: seg==1?Wtk: seg==2?Wtv: seg==3?Wvq: seg==4?Wvk: Wvv;
        WTall[(size_t)seg*65536 + r*256 + tid] = f2bf(Wsrc[tid*256 + r]);
    }
}

// ---------------- QKV projection via MFMA -> Qb row-major, Kf/Vf fragment-tiled ----------------
// Kf tile (bh, t16): 1KB, lane l holds K[k=t16*16+l%16][dk=8*(l/16)..+7] at l*16B.
// Vf tile (bh, t16, dh): 512B, lane l holds V[k=t16*16+4*(l/16)+j][d=dh*16+l%16] at l*8B.
__global__ __launch_bounds__(256, 2) void k_qkv(const float* __restrict__ src,
    const short* __restrict__ WTq, const short* __restrict__ WTk, const short* __restrict__ WTv,
    short* __restrict__ Qb, short* __restrict__ Kf, short* __restrict__ Vf, int is_txt)
{
    __shared__ __align__(16) short xb[3][16][256];   // 24 KB
    __shared__ float invf[128];
    __shared__ float lbs[128];
    int tid = threadIdx.x;
    int r0 = blockIdx.x * 16;
    int b, srow0;
    if (is_txt) { b = r0 >> 5;  srow0 = r0 & 31; }
    else        { b = r0 >> 10; srow0 = TXT_ + (r0 & 1023); }
    int t16 = srow0 >> 4;        // this block's k-tile index

    if (tid < 128) {
        float fk = (float)tid;
        invf[tid] = exp2f(-fk*(1.f/128.f)*LOG2_10000f);
        lbs[tid]  = log2f((2.f*fk + 102.4f) * (1.f/358.4f));
    }
    __syncthreads();

    #pragma unroll
    for (int it = 0; it < 8; ++it) {
        int task = it*256 + tid;
        int k  = task >> 4;
        int rr = task & 15;
        int srow = srow0 + rr;
        float2 x01 = ((const float2*)(src + ((size_t)b*S_ + srow)*DM_))[k];
        float a0, a1, c0, c1;
        if (is_txt) {
            float xe  = (float)(srow + 1) * (TWO_PIf/(32.f + 1e-6f));
            float arg = xe * invf[k];
            float sn = __sinf(arg), cs = __cosf(arg);
            a0 = x01.x + sn; a1 = x01.y + cs;
            c0 = a0; c1 = a1;
        } else {
            int l = srow - TXT_;
            float arg = (float)l * invf[k];
            float sn = __sinf(arg), cs = __cosf(arg);
            float scale = exp2f((float)l*(1.f/512.f)*lbs[k]);
            float rsc = 1.f/scale;
            float y0 = x01.x*cs - x01.y*sn;
            float y1 = x01.y*cs + x01.x*sn;
            a0 = y0*scale; a1 = y1*scale;
            c0 = y0*rsc;   c1 = y1*rsc;
        }
        int col = (2*k) ^ ((rr&7)<<3);
        *(short2*)&xb[0][rr][col] = make_short2(f2bf(a0), f2bf(a1));
        *(short2*)&xb[1][rr][col] = make_short2(f2bf(c0), f2bf(c1));
        *(short2*)&xb[2][rr][col] = make_short2(f2bf(x01.x), f2bf(x01.y));
    }
    __syncthreads();

    int lane = tid & 63;
    int w    = tid >> 6;
    int lr   = lane & 15;
    int lg   = lane >> 4;
    int swzl = (lr & 7) << 3;

    const short* WTs[3] = {WTq, WTk, WTv};
    #pragma unroll
    for (int m = 0; m < 3; ++m) {
        bf16x8 xf[8];
        #pragma unroll
        for (int kk = 0; kk < 8; ++kk)
            xf[kk] = *(const bf16x8*)&xb[m][lr][(kk*32 + lg*8) ^ swzl];
        #pragma unroll
        for (int ct = 0; ct < 4; ++ct) {
            int tb = (w + ct*4) * 16;
            const short* Wp = WTs[m] + (size_t)(tb+lr)*DM_ + lg*8;
            f32x4 acc = {0.f,0.f,0.f,0.f};
            if (m < 2) {
                #pragma unroll
                for (int kk = 0; kk < 8; ++kk) {
                    bf16x8 wf = *(const bf16x8*)(Wp + kk*32);
                    acc = __builtin_amdgcn_mfma_f32_16x16x32_bf16(wf, xf[kk], acc, 0, 0, 0);
                }
                // D: col=lane&15 = x-row(local), rows=(lg*4+c) = o-local d0..d0+3
                int h  = tb >> 5;
                int d0 = (tb & 31) + lg*4;
                short4 s4;
                if (m == 0) {
                    s4.x=f2bf(acc[0]*RSQRT_DKf); s4.y=f2bf(acc[1]*RSQRT_DKf);
                    s4.z=f2bf(acc[2]*RSQRT_DKf); s4.w=f2bf(acc[3]*RSQRT_DKf);
                    size_t off = ((size_t)(b*H_+h)*S_ + srow0+lr)*DK_ + d0;
                    *(short4*)&Qb[off] = s4;
                } else {
                    s4.x=f2bf(acc[0]); s4.y=f2bf(acc[1]);
                    s4.z=f2bf(acc[2]); s4.w=f2bf(acc[3]);
                    int lK = lr + 16*(d0 >> 3);   // fragment lane
                    *(short4*)&Kf[((((size_t)(b*H_+h)*NKT_ + t16) << 9)) + lK*8 + (d0 & 7)] = s4;
                }
            } else {
                #pragma unroll
                for (int kk = 0; kk < 8; ++kk) {
                    bf16x8 wf = *(const bf16x8*)(Wp + kk*32);
                    acc = __builtin_amdgcn_mfma_f32_16x16x32_bf16(xf[kk], wf, acc, 0, 0, 0);
                }
                // D: col=lane&15 = o-local(lr), rows=(lg*4+c) = x-row -> lane's Vf entry
                int o = tb + lr;
                int h = o >> 5;
                int dh = (tb >> 4) & 1;
                short4 s4;
                s4.x=f2bf(acc[0]); s4.y=f2bf(acc[1]);
                s4.z=f2bf(acc[2]); s4.w=f2bf(acc[3]);
                *(short4*)&Vf[((((size_t)(b*H_+h)*NKT_ + t16)*2 + dh) << 8) + lane*4] = s4;
            }
        }
    }
}

// ---------------- kernel A: denominators + ctx — in-lane PV, fragment-tiled operands ----------------
// ALL hot loads lane-contiguous: K 1KB/instr, V 512B, mask 512B (was 16-segment gathers).
#define CTX_TILE(KF, MV, VA, VB, PV0, PV1)                                        \
    {                                                                             \
        f32x4 acc = {0.f,0.f,0.f,0.f};                                            \
        acc = __builtin_amdgcn_mfma_f32_16x16x32_bf16(KF, qfrag, acc, 0, 0, 0);   \
        float e0 = __expf(acc[0]*bf2f(MV.x));                                     \
        float e1 = __expf(acc[1]*bf2f(MV.y));                                     \
        float e2 = __expf(acc[2]*bf2f(MV.z));                                     \
        float e3 = __expf(acc[3]*bf2f(MV.w));                                     \
        rssum += (e0+e1) + (e2+e3);                                               \
        bf16x4 pb; pb[0]=f2bf(e0); pb[1]=f2bf(e1); pb[2]=f2bf(e2); pb[3]=f2bf(e3);\
        PV0 = mfma16(pb, VA, PV0);                                                \
        PV1 = mfma16(pb, VB, PV1);                                                \
    }

__global__ __launch_bounds__(512, 2) void k_ctx(const short* __restrict__ Qb,
    const short* __restrict__ Kf, const short* __restrict__ Vf,
    const short* __restrict__ maskf, short* __restrict__ ctxb, float* __restrict__ denomG)
{
    int tid  = threadIdx.x;
    int lane = tid & 63;
    int w    = tid >> 6;          // wave = head
    int b    = blockIdx.x & 15;   // b-inner: XCD pinning (b%8)
    int qt   = blockIdx.x >> 4;   // 0..65
    int q0   = qt * 16;
    int lr   = lane & 15;
    int lg   = lane >> 4;

    const int bh = b*H_ + w;
    bf16x8 qfrag = *(const bf16x8*)(Qb + ((size_t)bh*S_ + q0 + lr)*DK_ + lg*8);
    const short* Kp = Kf + (((size_t)bh*NKT_) << 9) + lane*8;    // + t*512
    const short* Vp = Vf + (((size_t)bh*NKT_) << 9) + lane*4;    // + (t*2+dh)*256
    const short* Mp = maskf + (((size_t)qt*NKT_) << 8) + lane*4; // + t*256

    float rssum = 0.f;
    f32x4 pvA0 = {0.f,0.f,0.f,0.f}, pvA1 = {0.f,0.f,0.f,0.f};
    f32x4 pvB0 = {0.f,0.f,0.f,0.f}, pvB1 = {0.f,0.f,0.f,0.f};

    for (int g = 0; g < 11; ++g) {
        int tb = g * 6;           // 6 k-tiles (3 chunks) per group; 66 tiles total
        // ---- load batch: 24 lane-coalesced loads ----
        bf16x8 K[6]; ushort4 M[6]; short4 V[12];
        #pragma unroll
        for (int c = 0; c < 6; ++c) {
            int t = tb + c;
            K[c] = *(const bf16x8*)(Kp + (size_t)t*512);
            M[c] = *(const ushort4*)(Mp + (size_t)t*256);
            V[2*c]   = *(const short4*)(Vp + (size_t)(t*2  )*256);
            V[2*c+1] = *(const short4*)(Vp + (size_t)(t*2+1)*256);
        }
        // ---- compute 6 tiles ----
        #pragma unroll
        for (int c = 0; c < 3; ++c) {
            CTX_TILE(K[2*c],   M[2*c],   *(const bf16x4*)&V[4*c+0], *(const bf16x4*)&V[4*c+1], pvA0, pvA1)
            CTX_TILE(K[2*c+1], M[2*c+1], *(const bf16x4*)&V[4*c+2], *(const bf16x4*)&V[4*c+3], pvB0, pvB1)
        }
    }

    f32x4 pv0, pv1;
    pv0[0]=pvA0[0]+pvB0[0]; pv0[1]=pvA0[1]+pvB0[1]; pv0[2]=pvA0[2]+pvB0[2]; pv0[3]=pvA0[3]+pvB0[3];
    pv1[0]=pvA1[0]+pvB1[0]; pv1[1]=pvA1[1]+pvB1[1]; pv1[2]=pvA1[2]+pvB1[2]; pv1[3]=pvA1[3]+pvB1[3];

    // row sums: lane (lr,lg) holds partial for q=lr; reduce over lg
    rssum += __shfl_xor(rssum, 16, 64);
    rssum += __shfl_xor(rssum, 32, 64);
    float rd = 1.f / rssum;
    if (lane < 16)
        denomG[(size_t)bh*S_ + q0 + lane] = rd;

    // pv[r] = ctx[q=4lg+r][d=lr (pv0) / lr+16 (pv1)]
    #pragma unroll
    for (int r = 0; r < 4; ++r) {
        float rdq = __shfl(rd, 4*lg + r, 64);
        size_t off = ((size_t)b*S_ + q0 + 4*lg + r)*DM_ + w*DK_ + lr;
        ctxb[off]      = f2bf(pv0[r] * rdq);
        ctxb[off + 16] = f2bf(pv1[r] * rdq);
    }
}

// ---------------- kernel B: att by score recompute (Kf fragment loads) ----------------
__global__ __launch_bounds__(256, 4) void k_att(const short* __restrict__ Qb,
    const short* __restrict__ Kf, const short* __restrict__ maskb,
    const float* __restrict__ denomG, float* __restrict__ att)
{
    __shared__ float rd_l[8][16];
    int tid  = threadIdx.x;
    int lane = tid & 63;
    int w    = tid >> 6;
    int b    = blockIdx.x & 15;       // b-inner: XCD pinning
    int qt   = blockIdx.x >> 4;
    int q0   = qt * 16;

    if (tid < 128)
        rd_l[tid>>4][tid&15] = denomG[(size_t)(b*H_+(tid>>4))*S_ + q0 + (tid&15)] * 0.125f;
    __syncthreads();

    int lr = lane & 15;
    int lg = lane >> 4;

    bf16x8 qf[8];
    #pragma unroll
    for (int h = 0; h < 8; ++h)
        qf[h] = *(const bf16x8*)(Qb + ((size_t)(b*H_+h)*S_ + q0+lr)*DK_ + lg*8);

    int nt = (w < 2) ? 17 : 16;
    for (int t = 0; t < nt; ++t) {
        int kt = t*4 + w;             // k-tile index
        int k0 = kt*16;
        bf16x8 kf[8];
        #pragma unroll
        for (int h = 0; h < 8; ++h)
            kf[h] = *(const bf16x8*)(Kf + (((size_t)(b*H_+h)*NKT_ + kt) << 9) + lane*8);
        float m0 = bf2f((unsigned short)maskb[(size_t)(q0+4*lg+0)*S_ + k0+lr]);
        float m1 = bf2f((unsigned short)maskb[(size_t)(q0+4*lg+1)*S_ + k0+lr]);
        float m2 = bf2f((unsigned short)maskb[(size_t)(q0+4*lg+2)*S_ + k0+lr]);
        float m3 = bf2f((unsigned short)maskb[(size_t)(q0+4*lg+3)*S_ + k0+lr]);
        f32x4 a = {0.f,0.f,0.f,0.f};
        #pragma unroll
        for (int h = 0; h < 8; ++h) {
            f32x4 s = {0.f,0.f,0.f,0.f};
            s = __builtin_amdgcn_mfma_f32_16x16x32_bf16(qf[h], kf[h], s, 0, 0, 0);
            a[0] = fmaf(__expf(s[0]*m0), rd_l[h][4*lg+0], a[0]);
            a[1] = fmaf(__expf(s[1]*m1), rd_l[h][4*lg+1], a[1]);
            a[2] = fmaf(__expf(s[2]*m2), rd_l[h][4*lg+2], a[2]);
            a[3] = fmaf(__expf(s[3]*m3), rd_l[h][4*lg+3], a[3]);
        }
        att[((size_t)b*S_ + q0+4*lg+0)*S_ + k0+lr] = a[0];
        att[((size_t)b*S_ + q0+4*lg+1)*S_ + k0+lr] = a[1];
        att[((size_t)b*S_ + q0+4*lg+2)*S_ + k0+lr] = a[2];
        att[((size_t)b*S_ + q0+4*lg+3)*S_ + k0+lr] = a[3];
    }
}

// ---------------- out projection via MFMA (no LDS) ----------------
__global__ __launch_bounds__(256, 2) void k_outproj(const short* __restrict__ ctxb,
    const short* __restrict__ WoB, const float* __restrict__ bias, float* __restrict__ out)
{
    int tid  = threadIdx.x;
    int lane = tid & 63;
    int w    = tid >> 6;
    int lr   = lane & 15;
    int lg   = lane >> 4;
    int r0   = blockIdx.x * 16;

    bf16x8 cf[8];
    #pragma unroll
    for (int kk = 0; kk < 8; ++kk)
        cf[kk] = *(const bf16x8*)(ctxb + (size_t)(r0+lr)*DM_ + kk*32 + lg*8);

    #pragma unroll
    for (int ct = 0; ct < 4; ++ct) {
        int tb = (w + ct*4) * 16;
        const short* Wp = WoB + (size_t)(tb+lr)*DM_ + lg*8;
        f32x4 acc = {0.f,0.f,0.f,0.f};
        #pragma unroll
        for (int kk = 0; kk < 8; ++kk) {
            bf16x8 wf = *(const bf16x8*)(Wp + kk*32);
            acc = __builtin_amdgcn_mfma_f32_16x16x32_bf16(wf, cf[kk], acc, 0, 0, 0);
        }
        float4 b4 = *(const float4*)&bias[tb + lg*4];
        float4 o4 = make_float4(acc[0]+b4.x, acc[1]+b4.y, acc[2]+b4.z, acc[3]+b4.w);
        *(float4*)&out[(size_t)(r0+lr)*DM_ + tb + lg*4] = o4;
    }
}

extern "C" void kernel_launch(void* const* d_in, const int* in_sizes, int n_in,
                              void* d_out, int out_size, void* d_ws, size_t ws_size,
                              hipStream_t stream)
{
    (void)in_sizes; (void)n_in; (void)out_size; (void)ws_size;
    const float* src  = (const float*)d_in[0];
    const float* Wtq  = (const float*)d_in[1];
    const float* Wtk  = (const float*)d_in[2];
    const float* Wtv  = (const float*)d_in[3];
    const float* Wvq  = (const float*)d_in[4];
    const float* Wvk  = (const float*)d_in[5];
    const float* Wvv  = (const float*)d_in[6];
    const float* lvr  = (const float*)d_in[7];
    const float* Wout = (const float*)d_in[8];
    const float* bout = (const float*)d_in[9];
    const int*   rid  = (const int*)d_in[10];
    const int*   cid  = (const int*)d_in[11];

    const size_t QKV_SH = (size_t)B_*H_*S_*DK_;      // Qb shorts
    const size_t KF_SH  = (size_t)B_*H_*NKT_*512;    // Kf shorts (= QKV_SH)
    const size_t VF_SH  = (size_t)B_*H_*NKT_*512;    // Vf shorts
    const size_t CTX_SH = (size_t)B_*S_*DM_;

    float* ws       = (float*)d_ws;
    float* partials = ws;                             // MASK_BLKS
    float* denomG   = partials + MASK_BLKS;           // B*H*S
    short* maskf    = (short*)(denomG + (size_t)B_*H_*S_);
    short* maskb    = maskf + SS_;
    short* Qb       = maskb + SS_;
    short* Kf       = Qb + QKV_SH;
    short* Vf       = Kf + KF_SH;
    short* ctxb     = Vf + VF_SH;
    short* WTall    = ctxb + CTX_SH;                  // 6*65536
    short* WoB      = WTall + 6*65536;

    float* out  = (float*)d_out;
    float* att  = out + (size_t)B_*S_*DM_;
    float* loss = att + (size_t)B_*S_*S_;

    k_mask<<<MASK_BLKS, 256, 0, stream>>>(lvr, rid, cid, maskf, maskb, partials);
    k_wprep<<<7*256, 256, 0, stream>>>(Wtq, Wtk, Wtv, Wvq, Wvk, Wvv, Wout, WTall, WoB);
    k_qkv<<<(B_*TXT_)/16, 256, 0, stream>>>(src, WTall, WTall+65536, WTall+2*65536,
                                            Qb, Kf, Vf, 1);
    k_qkv<<<(B_*VID_)/16, 256, 0, stream>>>(src, WTall+3*65536, WTall+4*65536, WTall+5*65536,
                                            Qb, Kf, Vf, 0);
    k_ctx<<<B_*NQT_, 512, 0, stream>>>(Qb, Kf, Vf, maskf, ctxb, denomG);
    k_att<<<B_*NQT_, 256, 0, stream>>>(Qb, Kf, maskb, denomG, att);
    k_outproj<<<(B_*S_)/16, 256, 0, stream>>>(ctxb, WoB, bout, out);
    k_loss<<<1, 256, 0, stream>>>(partials, loss);
}